// Round 7
// baseline (686.045 us; speedup 1.0000x reference)
//
#include <hip/hip_runtime.h>
#include <hip/hip_bf16.h>
#include <math.h>

#define ALPHA 0.2f
// bucket = 128 consecutive dst nodes
#define BSHIFT 7
#define BSIZE 128

// ---------------- zero bucket counts ----------------
__global__ __launch_bounds__(1024) void k_bzero(int* __restrict__ bcnt, int nb) {
  int i = blockIdx.x * 1024 + threadIdx.x;
  if (i < nb) bcnt[i] = 0;
}

// ---------------- tiled fp32 GEMM: hw = h @ W ---------------- (unchanged)
__global__ __launch_bounds__(256) void k_gemm(const float* __restrict__ h,
                                              const float* __restrict__ W,
                                              float* __restrict__ hw, int N) {
  __shared__ float hsT[32 * 132];
  __shared__ float ws[32 * 64];
  const int tid = threadIdx.x;
  const int c0 = (tid & 15) * 4;
  const int r0 = (tid >> 4) * 8;
  const int row0 = blockIdx.x * 128;
  float acc[8][4] = {};
  for (int k0 = 0; k0 < 256; k0 += 32) {
    __syncthreads();
    #pragma unroll
    for (int s = 0; s < 4; ++s) {
      int f = tid + 256 * s;
      int r = f >> 3, kk = (f & 7) * 4;
      int row = row0 + r;
      float4 v = make_float4(0.f, 0.f, 0.f, 0.f);
      if (row < N) v = *(const float4*)(h + (size_t)row * 256 + k0 + kk);
      hsT[(kk + 0) * 132 + r] = v.x;
      hsT[(kk + 1) * 132 + r] = v.y;
      hsT[(kk + 2) * 132 + r] = v.z;
      hsT[(kk + 3) * 132 + r] = v.w;
    }
    #pragma unroll
    for (int s = 0; s < 2; ++s) {
      int f = tid + 256 * s;
      int kk = f >> 4, cc = (f & 15) * 4;
      *(float4*)(ws + kk * 64 + cc) =
          *(const float4*)(W + (size_t)(k0 + kk) * 64 + cc);
    }
    __syncthreads();
    #pragma unroll
    for (int k = 0; k < 32; ++k) {
      float4 wv = *(const float4*)(ws + k * 64 + c0);
      float4 ha = *(const float4*)(hsT + k * 132 + r0);
      float4 hb = *(const float4*)(hsT + k * 132 + r0 + 4);
      float hv[8] = {ha.x, ha.y, ha.z, ha.w, hb.x, hb.y, hb.z, hb.w};
      float wf[4] = {wv.x, wv.y, wv.z, wv.w};
      #pragma unroll
      for (int i = 0; i < 8; ++i)
        #pragma unroll
        for (int j = 0; j < 4; ++j)
          acc[i][j] = fmaf(hv[i], wf[j], acc[i][j]);
    }
  }
  #pragma unroll
  for (int i = 0; i < 8; ++i) {
    int row = row0 + r0 + i;
    if (row < N) {
      float4 o = make_float4(acc[i][0], acc[i][1], acc[i][2], acc[i][3]);
      *(float4*)(hw + (size_t)row * 64 + c0) = o;
    }
  }
}

// ---------------- s1/s2 = hw . a[:64], hw . a[64:] ---------------- (unchanged)
__global__ __launch_bounds__(256) void k_s(const float* __restrict__ hw,
                                           const float* __restrict__ a,
                                           float* __restrict__ s1,
                                           float* __restrict__ s2, int N) {
  int n = blockIdx.x * 4 + (threadIdx.x >> 6);
  int lane = threadIdx.x & 63;
  if (n >= N) return;
  float v = hw[(size_t)n * 64 + lane];
  float p1 = v * a[lane];
  float p2 = v * a[64 + lane];
  #pragma unroll
  for (int o = 32; o; o >>= 1) {
    p1 += __shfl_xor(p1, o);
    p2 += __shfl_xor(p2, o);
  }
  if (lane == 0) { s1[n] = p1; s2[n] = p2; }
}

// ---------------- bucket histogram (LDS-staged) ----------------
__global__ __launch_bounds__(256) void k_bcount(const int* __restrict__ dst,
                                                int* __restrict__ bcnt,
                                                int E, int nb) {
  __shared__ int lh[1024];
  int tid = threadIdx.x;
  for (int i = tid; i < 1024; i += 256) lh[i] = 0;
  __syncthreads();
  for (int e = blockIdx.x * 256 + tid; e < E; e += gridDim.x * 256)
    atomicAdd(lh + (dst[e] >> BSHIFT), 1);
  __syncthreads();
  for (int i = tid; i < nb; i += 256) {
    int c = lh[i];
    if (c) atomicAdd(bcnt + i, c);
  }
}

// ---------------- bucket exclusive scan (single block) ----------------
__global__ __launch_bounds__(1024) void k_bscan(const int* __restrict__ bcnt,
                                                int* __restrict__ boff,
                                                int* __restrict__ bcur,
                                                int* __restrict__ offsets,
                                                int nb, int N, int E) {
  __shared__ int sc[1024];
  int tid = threadIdx.x;
  sc[tid] = (tid < nb) ? bcnt[tid] : 0;
  __syncthreads();
  for (int o = 1; o < 1024; o <<= 1) {
    int t = 0;
    if (tid >= o) t = sc[tid - o];
    __syncthreads();
    if (tid >= o) sc[tid] += t;
    __syncthreads();
  }
  int excl = (tid > 0) ? sc[tid - 1] : 0;
  if (tid < nb) { boff[tid] = excl; bcur[tid] = excl; }
  if (tid == 0) { boff[nb] = E; offsets[N] = E; }
}

// ---------------- scatter edges into buckets (packed int) ----------------
// pack: (dst & 127) << 17 | src     (src < 2^17)
__global__ __launch_bounds__(256) void k_bscatter(const int* __restrict__ dst,
                                                  const int* __restrict__ src,
                                                  int* __restrict__ bcur,
                                                  int* __restrict__ binned,
                                                  int E) {
  int e = blockIdx.x * 256 + threadIdx.x;
  if (e >= E) return;
  int d = dst[e];
  int pos = atomicAdd(bcur + (d >> BSHIFT), 1);
  binned[pos] = ((d & (BSIZE - 1)) << 17) | src[e];
}

// ---------------- per-bucket CSR build: offsets + csr ----------------
// one block per bucket; all csr writes land in an ~8KB window -> coalesced
__global__ __launch_bounds__(256) void k_build(const int* __restrict__ boff,
                                               const int* __restrict__ binned,
                                               int* __restrict__ offsets,
                                               int* __restrict__ csr, int N) {
  __shared__ int cnt[BSIZE];
  __shared__ int sc[BSIZE];
  __shared__ int cur[BSIZE];
  const int b = blockIdx.x;
  const int tid = threadIdx.x;
  const int e0 = boff[b], e1 = boff[b + 1];
  if (tid < BSIZE) cnt[tid] = 0;
  __syncthreads();
  for (int e = e0 + tid; e < e1; e += 256)
    atomicAdd(cnt + (binned[e] >> 17), 1);
  __syncthreads();
  if (tid < BSIZE) sc[tid] = cnt[tid];
  __syncthreads();
  for (int o = 1; o < BSIZE; o <<= 1) {
    int t = 0;
    if (tid < BSIZE && tid >= o) t = sc[tid - o];
    __syncthreads();
    if (tid < BSIZE && tid >= o) sc[tid] += t;
    __syncthreads();
  }
  if (tid < BSIZE) {
    int excl = (tid > 0) ? sc[tid - 1] : 0;
    int abs0 = e0 + excl;
    int n = (b << BSHIFT) + tid;
    if (n < N) offsets[n] = abs0;
    cur[tid] = abs0;
  }
  __syncthreads();
  for (int e = e0 + tid; e < e1; e += 256) {
    int v = binned[e];
    int pos = atomicAdd(cur + (v >> 17), 1);
    csr[pos] = v & 0x1FFFF;
  }
}

// ---------------- per-node softmax + aggregation + ELU ---------------- (unchanged)
__global__ __launch_bounds__(256) void k_node(const int* __restrict__ off,
                                              const int* __restrict__ csr,
                                              const float* __restrict__ s1,
                                              const float* __restrict__ s2,
                                              const float* __restrict__ hw,
                                              float* __restrict__ out, int N) {
  int n = blockIdx.x * 4 + (threadIdx.x >> 6);
  int lane = threadIdx.x & 63;
  if (n >= N) return;
  int o0 = off[n], o1 = off[n + 1];
  int deg = o1 - o0;
  float4* out4 = (float4*)(out + (size_t)n * 64);
  if (deg == 0) {
    if (lane < 16) out4[lane] = make_float4(0.f, 0.f, 0.f, 0.f);
    return;
  }
  float s1n = s1[n];
  if (deg <= 64) {
    bool valid = lane < deg;
    int sj = valid ? csr[o0 + lane] : 0;
    float v = -INFINITY;
    if (valid) {
      v = s1n + s2[sj];
      v = v > 0.f ? v : ALPHA * v;
    }
    float m = v;
    #pragma unroll
    for (int o = 32; o; o >>= 1) m = fmaxf(m, __shfl_xor(m, o));
    float ex = valid ? expf(v - m) : 0.f;
    float es = ex;
    #pragma unroll
    for (int o = 32; o; o >>= 1) es += __shfl_xor(es, o);
    const int grp = lane >> 4, ch = lane & 15;
    const float4* hw4 = (const float4*)hw;
    float4 acc = make_float4(0.f, 0.f, 0.f, 0.f);
    for (int j0 = 0; j0 < deg; j0 += 4) {
      int e = j0 + grp;
      float exj = __shfl(ex, e & 63);
      int sjj = __shfl(sj, e & 63);
      if (e < deg) {
        float4 vv = hw4[(size_t)sjj * 16 + ch];
        acc.x = fmaf(exj, vv.x, acc.x);
        acc.y = fmaf(exj, vv.y, acc.y);
        acc.z = fmaf(exj, vv.z, acc.z);
        acc.w = fmaf(exj, vv.w, acc.w);
      }
    }
    acc.x += __shfl_xor(acc.x, 16);
    acc.y += __shfl_xor(acc.y, 16);
    acc.z += __shfl_xor(acc.z, 16);
    acc.w += __shfl_xor(acc.w, 16);
    acc.x += __shfl_xor(acc.x, 32);
    acc.y += __shfl_xor(acc.y, 32);
    acc.z += __shfl_xor(acc.z, 32);
    acc.w += __shfl_xor(acc.w, 32);
    if (lane < 16) {
      float inv = 1.f / es;
      float4 r;
      r.x = acc.x * inv; r.x = r.x > 0.f ? r.x : expm1f(r.x);
      r.y = acc.y * inv; r.y = r.y > 0.f ? r.y : expm1f(r.y);
      r.z = acc.z * inv; r.z = r.z > 0.f ? r.z : expm1f(r.z);
      r.w = acc.w * inv; r.w = r.w > 0.f ? r.w : expm1f(r.w);
      out4[lane] = r;
    }
  } else {
    float lm = -INFINITY;
    for (int j = lane; j < deg; j += 64) {
      int sj = csr[o0 + j];
      float v = s1n + s2[sj];
      v = v > 0.f ? v : ALPHA * v;
      lm = fmaxf(lm, v);
    }
    #pragma unroll
    for (int o = 32; o; o >>= 1) lm = fmaxf(lm, __shfl_xor(lm, o));
    float m = lm, les = 0.f, acc = 0.f;
    for (int j0 = 0; j0 < deg; j0 += 64) {
      int jj = j0 + lane;
      bool valid = jj < deg;
      int sj = valid ? csr[o0 + jj] : 0;
      float ex = 0.f;
      if (valid) {
        float v = s1n + s2[sj];
        v = v > 0.f ? v : ALPHA * v;
        ex = expf(v - m);
      }
      les += ex;
      int lim = min(64, deg - j0);
      for (int j = 0; j < lim; ++j) {
        float exj = __shfl(ex, j);
        int sjj = __shfl(sj, j);
        acc = fmaf(exj, hw[(size_t)sjj * 64 + lane], acc);
      }
    }
    #pragma unroll
    for (int o = 32; o; o >>= 1) les += __shfl_xor(les, o);
    float r = acc / les;
    out[(size_t)n * 64 + lane] = r > 0.f ? r : expm1f(r);
  }
}

extern "C" void kernel_launch(void* const* d_in, const int* in_sizes, int n_in,
                              void* d_out, int out_size, void* d_ws, size_t ws_size,
                              hipStream_t stream) {
  const float* h = (const float*)d_in[0];
  const float* W = (const float*)d_in[1];
  const float* a = (const float*)d_in[2];
  const int* dst = (const int*)d_in[3];
  const int* src = (const int*)d_in[4];
  float* out = (float*)d_out;
  const int N = in_sizes[0] / 256;
  const int E = in_sizes[3];
  const int nb = (N + BSIZE - 1) >> BSHIFT;   // buckets (782 for N=100K)

  char* p = (char*)d_ws;
  float* hw = (float*)p;      p += (size_t)N * 64 * sizeof(float);
  int* csr = (int*)p;         p += (size_t)E * sizeof(int);
  int* binned = (int*)p;      p += (size_t)E * sizeof(int);
  float* s1 = (float*)p;      p += (size_t)N * sizeof(float);
  float* s2 = (float*)p;      p += (size_t)N * sizeof(float);
  int* offsets = (int*)p;     p += ((size_t)N + 4) * sizeof(int);
  int* bcnt = (int*)p;        p += ((size_t)nb + 4) * sizeof(int);
  int* boff = (int*)p;        p += ((size_t)nb + 4) * sizeof(int);
  int* bcur = (int*)p;        p += ((size_t)nb + 4) * sizeof(int);

  const int nbE = (E + 255) / 256;

  k_bzero<<<(nb + 1023) / 1024, 1024, 0, stream>>>(bcnt, nb);
  k_gemm<<<(N + 127) / 128, 256, 0, stream>>>(h, W, hw, N);
  k_s<<<(N + 3) / 4, 256, 0, stream>>>(hw, a, s1, s2, N);
  k_bcount<<<512, 256, 0, stream>>>(dst, bcnt, E, nb);
  k_bscan<<<1, 1024, 0, stream>>>(bcnt, boff, bcur, offsets, nb, N, E);
  k_bscatter<<<nbE, 256, 0, stream>>>(dst, src, bcur, binned, E);
  k_build<<<nb, 256, 0, stream>>>(boff, binned, offsets, csr, N);
  k_node<<<(N + 3) / 4, 256, 0, stream>>>(offsets, csr, s1, s2, hw, out, N);
}

// Round 10
// 336.158 us; speedup vs baseline: 2.0408x; 2.0408x over previous
//
#include <hip/hip_runtime.h>
#include <hip/hip_bf16.h>
#include <math.h>

#define ALPHA 0.2f
// bucket = 1024 consecutive dst nodes
#define BSHIFT 10
#define BSIZE 1024
#define MAXB 128          // >= nb (98 for N=100K)
#define TILE 4096         // edges per k_bscatter block

// ---------------- zero bucket counts ----------------
__global__ __launch_bounds__(256) void k_bzero(int* __restrict__ bcnt, int nb) {
  int i = blockIdx.x * 256 + threadIdx.x;
  if (i < nb) bcnt[i] = 0;
}

// ---------------- tiled fp32 GEMM: hw = h @ W ---------------- (unchanged)
__global__ __launch_bounds__(256) void k_gemm(const float* __restrict__ h,
                                              const float* __restrict__ W,
                                              float* __restrict__ hw, int N) {
  __shared__ float hsT[32 * 132];
  __shared__ float ws[32 * 64];
  const int tid = threadIdx.x;
  const int c0 = (tid & 15) * 4;
  const int r0 = (tid >> 4) * 8;
  const int row0 = blockIdx.x * 128;
  float acc[8][4] = {};
  for (int k0 = 0; k0 < 256; k0 += 32) {
    __syncthreads();
    #pragma unroll
    for (int s = 0; s < 4; ++s) {
      int f = tid + 256 * s;
      int r = f >> 3, kk = (f & 7) * 4;
      int row = row0 + r;
      float4 v = make_float4(0.f, 0.f, 0.f, 0.f);
      if (row < N) v = *(const float4*)(h + (size_t)row * 256 + k0 + kk);
      hsT[(kk + 0) * 132 + r] = v.x;
      hsT[(kk + 1) * 132 + r] = v.y;
      hsT[(kk + 2) * 132 + r] = v.z;
      hsT[(kk + 3) * 132 + r] = v.w;
    }
    #pragma unroll
    for (int s = 0; s < 2; ++s) {
      int f = tid + 256 * s;
      int kk = f >> 4, cc = (f & 15) * 4;
      *(float4*)(ws + kk * 64 + cc) =
          *(const float4*)(W + (size_t)(k0 + kk) * 64 + cc);
    }
    __syncthreads();
    #pragma unroll
    for (int k = 0; k < 32; ++k) {
      float4 wv = *(const float4*)(ws + k * 64 + c0);
      float4 ha = *(const float4*)(hsT + k * 132 + r0);
      float4 hb = *(const float4*)(hsT + k * 132 + r0 + 4);
      float hv[8] = {ha.x, ha.y, ha.z, ha.w, hb.x, hb.y, hb.z, hb.w};
      float wf[4] = {wv.x, wv.y, wv.z, wv.w};
      #pragma unroll
      for (int i = 0; i < 8; ++i)
        #pragma unroll
        for (int j = 0; j < 4; ++j)
          acc[i][j] = fmaf(hv[i], wf[j], acc[i][j]);
    }
  }
  #pragma unroll
  for (int i = 0; i < 8; ++i) {
    int row = row0 + r0 + i;
    if (row < N) {
      float4 o = make_float4(acc[i][0], acc[i][1], acc[i][2], acc[i][3]);
      *(float4*)(hw + (size_t)row * 64 + c0) = o;
    }
  }
}

// ---------------- s1/s2 = hw . a[:64], hw . a[64:] ---------------- (unchanged)
__global__ __launch_bounds__(256) void k_s(const float* __restrict__ hw,
                                           const float* __restrict__ a,
                                           float* __restrict__ s1,
                                           float* __restrict__ s2, int N) {
  int n = blockIdx.x * 4 + (threadIdx.x >> 6);
  int lane = threadIdx.x & 63;
  if (n >= N) return;
  float v = hw[(size_t)n * 64 + lane];
  float p1 = v * a[lane];
  float p2 = v * a[64 + lane];
  #pragma unroll
  for (int o = 32; o; o >>= 1) {
    p1 += __shfl_xor(p1, o);
    p2 += __shfl_xor(p2, o);
  }
  if (lane == 0) { s1[n] = p1; s2[n] = p2; }
}

// ---------------- bucket histogram (LDS-staged, 98 counters) ----------------
__global__ __launch_bounds__(256) void k_bcount(const int* __restrict__ dst,
                                                int* __restrict__ bcnt,
                                                int E, int nb) {
  __shared__ int lh[MAXB];
  int tid = threadIdx.x;
  for (int i = tid; i < MAXB; i += 256) lh[i] = 0;
  __syncthreads();
  for (int e = blockIdx.x * 256 + tid; e < E; e += gridDim.x * 256)
    atomicAdd(lh + (dst[e] >> BSHIFT), 1);
  __syncthreads();
  for (int i = tid; i < nb; i += 256) {
    int c = lh[i];
    if (c) atomicAdd(bcnt + i, c);
  }
}

// ---------------- bucket exclusive scan (single block) ----------------
__global__ __launch_bounds__(128) void k_bscan(const int* __restrict__ bcnt,
                                               int* __restrict__ boff,
                                               int* __restrict__ bcur,
                                               int* __restrict__ offsets,
                                               int nb, int N, int E) {
  __shared__ int sc[MAXB];
  int tid = threadIdx.x;
  sc[tid] = (tid < nb) ? bcnt[tid] : 0;
  __syncthreads();
  for (int o = 1; o < MAXB; o <<= 1) {
    int t = 0;
    if (tid >= o) t = sc[tid - o];
    __syncthreads();
    if (tid >= o) sc[tid] += t;
    __syncthreads();
  }
  int excl = (tid > 0) ? sc[tid - 1] : 0;
  if (tid < nb) { boff[tid] = excl; bcur[tid] = excl; }
  if (tid == 0) { boff[nb] = E; offsets[N] = E; }
}

// ---------------- LDS-binned scatter: bucket-grouped runs, coalesced flush --
// pack: (dst & 1023) << 17 | src   (src < 2^17)
__global__ __launch_bounds__(256) void k_bscatter(const int* __restrict__ dst,
                                                  const int* __restrict__ src,
                                                  int* __restrict__ bcur,
                                                  int* __restrict__ binned,
                                                  int E) {
  __shared__ int lcnt[MAXB];
  __shared__ int loff[MAXB];
  __shared__ int lcur[MAXB];
  __shared__ int gdelta[MAXB];
  __shared__ int lstage[TILE];
  __shared__ unsigned char lbb[TILE];
  const int tid = threadIdx.x;
  const int base = blockIdx.x * TILE;
  const int cnt_here = min(TILE, E - base);
  int myb[TILE / 256];
  int myp[TILE / 256];
  #pragma unroll
  for (int i = 0; i < TILE / 256; ++i) {
    int e = base + i * 256 + tid;
    if (e < E) {
      int d = dst[e];
      myb[i] = d >> BSHIFT;
      myp[i] = ((d & (BSIZE - 1)) << 17) | src[e];
    } else
      myb[i] = -1;
  }
  for (int i = tid; i < MAXB; i += 256) lcnt[i] = 0;
  __syncthreads();
  #pragma unroll
  for (int i = 0; i < TILE / 256; ++i)
    if (myb[i] >= 0) atomicAdd(lcnt + myb[i], 1);
  __syncthreads();
  // exclusive scan over MAXB buckets (threads 0..127)
  if (tid < MAXB) loff[tid] = lcnt[tid];
  __syncthreads();
  for (int o = 1; o < MAXB; o <<= 1) {
    int t = 0;
    if (tid < MAXB && tid >= o) t = loff[tid - o];
    __syncthreads();
    if (tid < MAXB && tid >= o) loff[tid] += t;
    __syncthreads();
  }
  if (tid < MAXB) {
    int excl = (tid > 0) ? loff[tid - 1] : 0;
    lcur[tid] = excl;
    int c = lcnt[tid];
    gdelta[tid] = (c > 0) ? (atomicAdd(bcur + tid, c) - excl) : 0;
  }
  __syncthreads();
  // place into bucket-grouped LDS runs
  #pragma unroll
  for (int i = 0; i < TILE / 256; ++i)
    if (myb[i] >= 0) {
      int p = atomicAdd(lcur + myb[i], 1);
      lstage[p] = myp[i];
      lbb[p] = (unsigned char)myb[i];
    }
  __syncthreads();
  // coalesced flush: consecutive idx within a run -> consecutive global
  for (int idx = tid; idx < cnt_here; idx += 256) {
    int b = lbb[idx];
    binned[gdelta[b] + idx] = lstage[idx];
  }
}

// ---------------- per-bucket CSR build: offsets + csr ----------------
// one 1024-thread block per bucket; csr writes land in a ~65KB window
__global__ __launch_bounds__(1024) void k_build(const int* __restrict__ boff,
                                                const int* __restrict__ binned,
                                                int* __restrict__ offsets,
                                                int* __restrict__ csr, int N) {
  __shared__ int cnt[BSIZE];
  __shared__ int sc[BSIZE];
  __shared__ int cur[BSIZE];
  const int b = blockIdx.x;
  const int tid = threadIdx.x;
  const int e0 = boff[b], e1 = boff[b + 1];
  cnt[tid] = 0;
  __syncthreads();
  for (int e = e0 + tid; e < e1; e += 1024)
    atomicAdd(cnt + (binned[e] >> 17), 1);
  __syncthreads();
  sc[tid] = cnt[tid];
  __syncthreads();
  for (int o = 1; o < BSIZE; o <<= 1) {
    int t = 0;
    if (tid >= o) t = sc[tid - o];
    __syncthreads();
    if (tid >= o) sc[tid] += t;
    __syncthreads();
  }
  {
    int excl = (tid > 0) ? sc[tid - 1] : 0;
    int abs0 = e0 + excl;
    int n = (b << BSHIFT) + tid;
    if (n < N) offsets[n] = abs0;
    cur[tid] = abs0;
  }
  __syncthreads();
  for (int e = e0 + tid; e < e1; e += 1024) {
    int v = binned[e];
    int pos = atomicAdd(cur + (v >> 17), 1);
    csr[pos] = v & 0x1FFFF;
  }
}

// ---------------- per-node softmax + aggregation + ELU ---------------- (unchanged)
__global__ __launch_bounds__(256) void k_node(const int* __restrict__ off,
                                              const int* __restrict__ csr,
                                              const float* __restrict__ s1,
                                              const float* __restrict__ s2,
                                              const float* __restrict__ hw,
                                              float* __restrict__ out, int N) {
  int n = blockIdx.x * 4 + (threadIdx.x >> 6);
  int lane = threadIdx.x & 63;
  if (n >= N) return;
  int o0 = off[n], o1 = off[n + 1];
  int deg = o1 - o0;
  float4* out4 = (float4*)(out + (size_t)n * 64);
  if (deg == 0) {
    if (lane < 16) out4[lane] = make_float4(0.f, 0.f, 0.f, 0.f);
    return;
  }
  float s1n = s1[n];
  if (deg <= 64) {
    bool valid = lane < deg;
    int sj = valid ? csr[o0 + lane] : 0;
    float v = -INFINITY;
    if (valid) {
      v = s1n + s2[sj];
      v = v > 0.f ? v : ALPHA * v;
    }
    float m = v;
    #pragma unroll
    for (int o = 32; o; o >>= 1) m = fmaxf(m, __shfl_xor(m, o));
    float ex = valid ? expf(v - m) : 0.f;
    float es = ex;
    #pragma unroll
    for (int o = 32; o; o >>= 1) es += __shfl_xor(es, o);
    const int grp = lane >> 4, ch = lane & 15;
    const float4* hw4 = (const float4*)hw;
    float4 acc = make_float4(0.f, 0.f, 0.f, 0.f);
    for (int j0 = 0; j0 < deg; j0 += 4) {
      int e = j0 + grp;
      float exj = __shfl(ex, e & 63);
      int sjj = __shfl(sj, e & 63);
      if (e < deg) {
        float4 vv = hw4[(size_t)sjj * 16 + ch];
        acc.x = fmaf(exj, vv.x, acc.x);
        acc.y = fmaf(exj, vv.y, acc.y);
        acc.z = fmaf(exj, vv.z, acc.z);
        acc.w = fmaf(exj, vv.w, acc.w);
      }
    }
    acc.x += __shfl_xor(acc.x, 16);
    acc.y += __shfl_xor(acc.y, 16);
    acc.z += __shfl_xor(acc.z, 16);
    acc.w += __shfl_xor(acc.w, 16);
    acc.x += __shfl_xor(acc.x, 32);
    acc.y += __shfl_xor(acc.y, 32);
    acc.z += __shfl_xor(acc.z, 32);
    acc.w += __shfl_xor(acc.w, 32);
    if (lane < 16) {
      float inv = 1.f / es;
      float4 r;
      r.x = acc.x * inv; r.x = r.x > 0.f ? r.x : expm1f(r.x);
      r.y = acc.y * inv; r.y = r.y > 0.f ? r.y : expm1f(r.y);
      r.z = acc.z * inv; r.z = r.z > 0.f ? r.z : expm1f(r.z);
      r.w = acc.w * inv; r.w = r.w > 0.f ? r.w : expm1f(r.w);
      out4[lane] = r;
    }
  } else {
    float lm = -INFINITY;
    for (int j = lane; j < deg; j += 64) {
      int sj = csr[o0 + j];
      float v = s1n + s2[sj];
      v = v > 0.f ? v : ALPHA * v;
      lm = fmaxf(lm, v);
    }
    #pragma unroll
    for (int o = 32; o; o >>= 1) lm = fmaxf(lm, __shfl_xor(lm, o));
    float m = lm, les = 0.f, acc = 0.f;
    for (int j0 = 0; j0 < deg; j0 += 64) {
      int jj = j0 + lane;
      bool valid = jj < deg;
      int sj = valid ? csr[o0 + jj] : 0;
      float ex = 0.f;
      if (valid) {
        float v = s1n + s2[sj];
        v = v > 0.f ? v : ALPHA * v;
        ex = expf(v - m);
      }
      les += ex;
      int lim = min(64, deg - j0);
      for (int j = 0; j < lim; ++j) {
        float exj = __shfl(ex, j);
        int sjj = __shfl(sj, j);
        acc = fmaf(exj, hw[(size_t)sjj * 64 + lane], acc);
      }
    }
    #pragma unroll
    for (int o = 32; o; o >>= 1) les += __shfl_xor(les, o);
    float r = acc / les;
    out[(size_t)n * 64 + lane] = r > 0.f ? r : expm1f(r);
  }
}

extern "C" void kernel_launch(void* const* d_in, const int* in_sizes, int n_in,
                              void* d_out, int out_size, void* d_ws, size_t ws_size,
                              hipStream_t stream) {
  const float* h = (const float*)d_in[0];
  const float* W = (const float*)d_in[1];
  const float* a = (const float*)d_in[2];
  const int* dst = (const int*)d_in[3];
  const int* src = (const int*)d_in[4];
  float* out = (float*)d_out;
  const int N = in_sizes[0] / 256;
  const int E = in_sizes[3];
  const int nb = (N + BSIZE - 1) >> BSHIFT;  // 98 buckets for N=100K

  char* p = (char*)d_ws;
  float* hw = (float*)p;    p += (size_t)N * 64 * sizeof(float);
  int* csr = (int*)p;       p += (size_t)E * sizeof(int);
  int* binned = (int*)p;    p += (size_t)E * sizeof(int);
  float* s1 = (float*)p;    p += (size_t)N * sizeof(float);
  float* s2 = (float*)p;    p += (size_t)N * sizeof(float);
  int* offsets = (int*)p;   p += ((size_t)N + 4) * sizeof(int);
  int* bcnt = (int*)p;      p += MAXB * sizeof(int);
  int* boff = (int*)p;      p += (MAXB + 4) * sizeof(int);
  int* bcur = (int*)p;      p += MAXB * sizeof(int);

  k_bzero<<<1, 256, 0, stream>>>(bcnt, nb);
  k_gemm<<<(N + 127) / 128, 256, 0, stream>>>(h, W, hw, N);
  k_s<<<(N + 3) / 4, 256, 0, stream>>>(hw, a, s1, s2, N);
  k_bcount<<<512, 256, 0, stream>>>(dst, bcnt, E, nb);
  k_bscan<<<1, 128, 0, stream>>>(bcnt, boff, bcur, offsets, nb, N, E);
  k_bscatter<<<(E + TILE - 1) / TILE, 256, 0, stream>>>(dst, src, bcur, binned, E);
  k_build<<<nb, 1024, 0, stream>>>(boff, binned, offsets, csr, N);
  k_node<<<(N + 3) / 4, 256, 0, stream>>>(offsets, csr, s1, s2, hw, out, N);
}